// Round 4
// baseline (293.244 us; speedup 1.0000x reference)
//
#include <hip/hip_runtime.h>
#include <hip/hip_bf16.h>

// B=8, T=1024, D=512, H=8, DH=64, VS=512
typedef __bf16 bf16;
typedef __bf16 bf16x8 __attribute__((ext_vector_type(8)));
typedef __bf16 bf16x4 __attribute__((ext_vector_type(4)));
typedef float f32x4 __attribute__((ext_vector_type(4)));

#define NEGBIG (-3.0e38f)

__device__ inline f32x4 mfma16(bf16x8 a, bf16x8 b, f32x4 c) {
    return __builtin_amdgcn_mfma_f32_16x16x32_bf16(a, b, c, 0, 0, 0);
}
__device__ inline bf16x8 ld8(const bf16* p) { return *reinterpret_cast<const bf16x8*>(p); }
__device__ inline f32x4 ldf4(const float* p) { return *reinterpret_cast<const f32x4*>(p); }

// ---------------- pe table: [2048][64] bf16 ----------------
__global__ void pe_kernel(bf16* __restrict__ pe_b) {
    int l = blockIdx.x, d = threadIdx.x;
    float pos = (float)(l - 1024);
    int k = d & 31;
    float dv = __expf(-(float)k * 0.29710775393471563f);   // ln(10000)/31
    float ang = pos * dv;
    float v = (d < 32) ? sinf(ang) : cosf(ang);
    pe_b[l * 64 + d] = (bf16)v;
}

// ---------------- vb table: [8][2048] fp32 ----------------
__global__ void vb_kernel(const float* __restrict__ v_bias, float* __restrict__ vb) {
    int t = blockIdx.x * 256 + threadIdx.x;   // h*2048 + l
    int h = t >> 11, l = t & 2047;
    float pos = (float)(l - 1024);
    float s = 0.f;
    #pragma unroll 4
    for (int d = 0; d < 32; d++) {
        float dv = __expf(-(float)d * 0.29710775393471563f);
        float ang = pos * dv;
        s += v_bias[h * 64 + d] * sinf(ang) + v_bias[h * 64 + 32 + d] * cosf(ang);
    }
    vb[t] = s;
}

// ---------------- key convert: fp32 [b][t][h*64+dh] -> bf16 [bh][t][dh] ----------------
__global__ void kcvt_kernel(const float* __restrict__ kin, bf16* __restrict__ kw) {
    int i = (blockIdx.x * 256 + threadIdx.x) * 4;   // 4.19M floats
    f32x4 v = ldf4(kin + i);
    int dh = i & 63, hh = (i >> 6) & 7, t = (i >> 9) & 1023, b = i >> 19;
    bf16x4 o;
    #pragma unroll
    for (int e = 0; e < 4; e++) o[e] = (bf16)v[e];
    *reinterpret_cast<bf16x4*>(kw + ((((b << 3) + hh) << 10) + t) * 64 + dh) = o;
}

// ---------------- 8192x512x512 GEMM + bias, bf16 MFMA, fp32 accum ----------------
// MODE 0: A fp32, out bf16 [((b*8+h)*1024+t)*64+dh]   (q_ws)
// MODE 2: A fp32, out bf16 [((b*8+h)*64+dh)*1024+t]   (v_ws TRANSPOSED)
// MODE 1: A bf16, out fp32 [row*512+col]              (d_out)
template<int MODE>
__global__ __launch_bounds__(256) void proj_gemm(const void* __restrict__ Ap, const float* __restrict__ W,
                                                 const float* __restrict__ bias, void* __restrict__ outp) {
    __shared__ bf16 As[64][40];
    __shared__ bf16 Wt[64][40];
    int row0 = blockIdx.x * 64, n0 = blockIdx.y * 64;
    int tid = threadIdx.x, lane = tid & 63, w = tid >> 6, lg = lane >> 4, lr = lane & 15;
    int wm = (w >> 1) * 32, wn = (w & 1) * 32;
    f32x4 acc[2][2] = {};
    for (int k0 = 0; k0 < 512; k0 += 32) {
        int r = tid >> 2, kq = (tid & 3) * 8;
        bf16x8 av;
        if (MODE != 1) {
            const float* A = (const float*)Ap;
            f32x4 a0 = ldf4(A + (row0 + r) * 512 + k0 + kq);
            f32x4 a1 = ldf4(A + (row0 + r) * 512 + k0 + kq + 4);
            #pragma unroll
            for (int e = 0; e < 4; e++) { av[e] = (bf16)a0[e]; av[4 + e] = (bf16)a1[e]; }
        } else {
            av = ld8((const bf16*)Ap + (row0 + r) * 512 + k0 + kq);
        }
        int kk = tid >> 3, n8 = (tid & 7) * 8;
        f32x4 w0 = ldf4(W + (k0 + kk) * 512 + n0 + n8);
        f32x4 w1 = ldf4(W + (k0 + kk) * 512 + n0 + n8 + 4);
        __syncthreads();
        *reinterpret_cast<bf16x8*>(&As[r][kq]) = av;
        #pragma unroll
        for (int e = 0; e < 4; e++) { Wt[n8 + e][kk] = (bf16)w0[e]; Wt[n8 + 4 + e][kk] = (bf16)w1[e]; }
        __syncthreads();
        bf16x8 a0 = ld8(&As[wm + lr][lg * 8]);
        bf16x8 a1 = ld8(&As[wm + 16 + lr][lg * 8]);
        bf16x8 b0 = ld8(&Wt[wn + lr][lg * 8]);
        bf16x8 b1 = ld8(&Wt[wn + 16 + lr][lg * 8]);
        acc[0][0] = mfma16(a0, b0, acc[0][0]);
        acc[0][1] = mfma16(a0, b1, acc[0][1]);
        acc[1][0] = mfma16(a1, b0, acc[1][0]);
        acc[1][1] = mfma16(a1, b1, acc[1][1]);
    }
    #pragma unroll
    for (int mi = 0; mi < 2; mi++)
    #pragma unroll
    for (int ni = 0; ni < 2; ni++) {
        int rowb = row0 + wm + mi * 16 + lg * 4;
        int col = n0 + wn + ni * 16 + lr;
        if (MODE == 2) {
            int b = rowb >> 10, t = rowb & 1023, hh = col >> 6, dh = col & 63;
            bf16x4 o4;
            #pragma unroll
            for (int rr = 0; rr < 4; rr++) o4[rr] = (bf16)((float)acc[mi][ni][rr] + bias[col]);
            *reinterpret_cast<bf16x4*>((bf16*)outp + ((((b << 3) + hh) << 6) + dh) * 1024 + t) = o4;
        } else {
            #pragma unroll
            for (int rr = 0; rr < 4; rr++) {
                int row = rowb + rr;
                float v = (float)acc[mi][ni][rr] + bias[col];
                if (MODE == 0) {
                    int b = row >> 10, t = row & 1023, hh = col >> 6, dh = col & 63;
                    ((bf16*)outp)[((((b << 3) + hh) << 10) + t) * 64 + dh] = (bf16)v;
                } else {
                    ((float*)outp)[row * 512 + col] = v;
                }
            }
        }
    }
}

// ---------------- fused TENER attention: 1 wave per block, no barriers ----------------
// grid: (64 bh, 64 q-tiles of 16 rows), block 64
__global__ __launch_bounds__(64) void tener_attn(const bf16* __restrict__ qw, const bf16* __restrict__ kw,
                                                 const bf16* __restrict__ vt, const int* __restrict__ mask,
                                                 const bf16* __restrict__ peb, const float* __restrict__ vb,
                                                 bf16* __restrict__ xw) {
    __shared__ bf16 Pl[16][76];        // wave-local P relayout (stride 76 -> bank-spread)
    int bh = blockIdx.x, b = bh >> 3, h = bh & 7;
    int rbase = blockIdx.y * 16;
    int lane = threadIdx.x, lg = lane >> 4, lr = lane & 15;

    const bf16* kbase = kw + (bh << 16);           // [t][dh]
    const bf16* vbase = vt + (bh << 16);           // [dh][t]
    const float* vbh  = vb + (h << 11);
    const int* mkb    = mask + (b << 10);

    bf16x8 aq0 = ld8(qw + ((bh << 10) + rbase + lr) * 64 + lg * 8);
    bf16x8 aq1 = ld8(qw + ((bh << 10) + rbase + lr) * 64 + 32 + lg * 8);

    f32x4 o[4] = {};
    float m_[4], d_[4];
    #pragma unroll
    for (int r = 0; r < 4; r++) { m_[r] = NEGBIG; d_[r] = 0.f; }

    for (int j0 = 0; j0 < 1024; j0 += 64) {
        int L0 = 1024 + j0 - rbase;

        // S = Q.K^T, fragments straight from global bf16 K
        f32x4 s[4];
        #pragma unroll
        for (int nt = 0; nt < 4; nt++) {
            const bf16* kp = kbase + (j0 + nt * 16 + lr) * 64 + lg * 8;
            f32x4 acc = {};
            acc = mfma16(aq0, ld8(kp), acc);
            acc = mfma16(aq1, ld8(kp + 32), acc);
            s[nt] = acc;
        }

        // R band + vb folded: Rg[ut][r] = Q[4lg+r].pe[L0-16+16ut+lr] + vb[h][L0-16+16ut+lr]
        f32x4 Rg[5];
        #pragma unroll
        for (int ut = 0; ut < 5; ut++) {
            int l = L0 - 16 + ut * 16 + lr;
            const bf16* pp = peb + l * 64 + lg * 8;
            f32x4 acc = {};
            acc = mfma16(aq0, ld8(pp), acc);
            acc = mfma16(aq1, ld8(pp + 32), acc);
            float vbv = vbh[l];
            #pragma unroll
            for (int r = 0; r < 4; r++) acc[r] += vbv;
            Rg[ut] = acc;
        }

        int mk[4];
        #pragma unroll
        for (int nt = 0; nt < 4; nt++) mk[nt] = mkb[j0 + nt * 16 + lr];

        // online softmax, rel gathered via in-register shuffles
        #pragma unroll
        for (int r = 0; r < 4; r++) {
            int rl = 4 * lg + r;
            int dlt = lr - rl;                       // [-15, 15]
            int src = (lg << 4) | (dlt & 15);
            float sh[5];
            #pragma unroll
            for (int ut = 0; ut < 5; ut++) sh[ut] = __shfl(Rg[ut][r], src, 64);
            float sv[4];
            #pragma unroll
            for (int nt = 0; nt < 4; nt++) {
                float rel = (dlt >= 0) ? sh[nt + 1] : sh[nt];
                sv[nt] = mk[nt] ? (float)s[nt][r] + rel : NEGBIG;
            }
            float mx = fmaxf(fmaxf(sv[0], sv[1]), fmaxf(sv[2], sv[3]));
            #pragma unroll
            for (int off = 1; off < 16; off <<= 1) mx = fmaxf(mx, __shfl_xor(mx, off));
            float nm = fmaxf(m_[r], mx);
            float sc = __expf(m_[r] - nm);
            float p[4], rs = 0.f;
            #pragma unroll
            for (int nt = 0; nt < 4; nt++) {
                p[nt] = mk[nt] ? __expf(sv[nt] - nm) : 0.f;
                rs += p[nt];
            }
            #pragma unroll
            for (int off = 1; off < 16; off <<= 1) rs += __shfl_xor(rs, off);
            d_[r] = d_[r] * sc + rs;
            m_[r] = nm;
            #pragma unroll
            for (int dt = 0; dt < 4; dt++) o[dt][r] *= sc;
            #pragma unroll
            for (int nt = 0; nt < 4; nt++) Pl[rl][nt * 16 + lr] = (bf16)p[nt];
        }

        // order Pl writes before reads (wave-local; rule-18 fence)
        asm volatile("s_waitcnt lgkmcnt(0)" ::: "memory");
        __builtin_amdgcn_sched_barrier(0);

        // O += P.V  (V^T fragments straight from global transposed v_ws)
        #pragma unroll
        for (int ks = 0; ks < 2; ks++) {
            bf16x8 ap = ld8(&Pl[lr][ks * 32 + lg * 8]);
            #pragma unroll
            for (int dt = 0; dt < 4; dt++) {
                const bf16* vp = vbase + (dt * 16 + lr) * 1024 + j0 + ks * 32 + lg * 8;
                o[dt] = mfma16(ap, ld8(vp), o[dt]);
            }
        }
        // next tile's Pl writes are after these reads in program order (in-order wave LDS)
    }

    // epilogue: x[b, row, h*64+dh] = O/d
    #pragma unroll
    for (int dt = 0; dt < 4; dt++)
    #pragma unroll
    for (int r = 0; r < 4; r++) {
        int row = rbase + 4 * lg + r;
        float denom = d_[r];
        float v = denom > 0.f ? (float)o[dt][r] / denom : 0.f;
        xw[(((b << 10) + row) << 9) + (h << 6) + dt * 16 + lr] = (bf16)v;
    }
}

extern "C" void kernel_launch(void* const* d_in, const int* in_sizes, int n_in,
                              void* d_out, int out_size, void* d_ws, size_t ws_size,
                              hipStream_t stream) {
    const float* query  = (const float*)d_in[0];
    const float* key_in = (const float*)d_in[1];
    const float* value  = (const float*)d_in[2];
    const int*   mask   = (const int*)d_in[3];
    const float* Wq     = (const float*)d_in[4];
    const float* bq     = (const float*)d_in[5];
    const float* Wv     = (const float*)d_in[6];
    const float* bv     = (const float*)d_in[7];
    const float* Wo     = (const float*)d_in[8];
    const float* bo     = (const float*)d_in[9];
    const float* v_bias = (const float*)d_in[10];

    char* ws = (char*)d_ws;
    bf16*  pe_b = (bf16*)(ws);                           // 256 KB
    float* vb   = (float*)(ws + 262144);                 // 64 KB
    bf16*  q_ws = (bf16*)(ws + 327680);                  // 8 MB  [bh][t][dh]
    bf16*  v_ws = (bf16*)(ws + 327680 + 8388608);        // 8 MB  [bh][dh][t] (transposed)
    bf16*  x_ws = (bf16*)(ws + 327680 + 16777216);       // 8 MB  [b*t][512]
    // k_ws lives in d_out's first 8 MB (d_out = 16 MB fp32); fully consumed by
    // tener_attn before proj_gemm<1> overwrites d_out at the end.
    bf16*  k_ws = (bf16*)d_out;

    pe_kernel<<<2048, 64, 0, stream>>>(pe_b);
    vb_kernel<<<64, 256, 0, stream>>>(v_bias, vb);
    kcvt_kernel<<<4096, 256, 0, stream>>>(key_in, k_ws);
    proj_gemm<0><<<dim3(128, 8), 256, 0, stream>>>(query, Wq, bq, q_ws);
    proj_gemm<2><<<dim3(128, 8), 256, 0, stream>>>(value, Wv, bv, v_ws);
    tener_attn<<<dim3(64, 64), 64, 0, stream>>>(q_ws, k_ws, v_ws, mask, pe_b, vb, x_ws);
    proj_gemm<1><<<dim3(128, 8), 256, 0, stream>>>(x_ws, Wo, bo, d_out);
}